// Round 4
// baseline (166.122 us; speedup 1.0000x reference)
//
#include <hip/hip_runtime.h>
#include <cfloat>
#include <cmath>

#define NPTS 131072
#define NC   512
#define NREP 4
#define L2E  1.4426950408889634f
#define LN2  0.6931471805599453f
// log2-domain relevance cutoff: gamma < 2^-34 contributes < 6e-11 per pair.
// Validated: rounds 0-3 all have identical absmax with/without this cut.
#define CUT  34.0f
#define WSL  256    // per-wave entry-slice capacity (mean ~42, 33-sigma margin)
#define ECAP (8 * WSL)
#define PK   15     // per-point id slots (overflow -> dense fallback in final)

// ws float-index layout:
//  PM4  [0, 2048)      : per-component float4, BASE-2 scaled
//  PQ4  [2048, 4096)   : per-component float4 (mu_new[3], A_c)
//  ST4  [4096, 12288)  : NREP replicas x 512 comps x float4 (Tx,Ty,Tz,S)
//  MISC [12288, 12296) : [0]=sum|x|^2, [1]=inv2s2_new, [3]=sum(gamma*lgamma)
//  PL   [16384, ...)   : per-point u16[16]: [cnt|0xFFFF, id0..id14]  (4 MB)
// z_n (base-2 units) staged in d_out[3n] (k_estep writes, k_final reads then overwrites).
#define PM4_OFF  0
#define PQ4_OFF  2048
#define ST4_OFF  4096
#define MISC_OFF 12288
#define PL_OFF   16384

__device__ __forceinline__ float waveSum(float v) {
#pragma unroll
  for (int off = 32; off > 0; off >>= 1) v += __shfl_down(v, off, 64);
  return v;
}
__device__ __forceinline__ float waveMax(float v) {
#pragma unroll
  for (int off = 32; off > 0; off >>= 1) v = fmaxf(v, __shfl_down(v, off, 64));
  return v;
}
__device__ __forceinline__ unsigned lanePrefix(unsigned long long m) {
  return __builtin_amdgcn_mbcnt_hi(
      (unsigned)(m >> 32), __builtin_amdgcn_mbcnt_lo((unsigned)m, 0u));
}

// Dense 32-comp sweep: unconditional sE/qE accumulate + register hit-bitmask.
// Shift-in keeps the bit position compile-time-free: comp j of this sweep
// ends at bit j after all 32 iterations. No branches, no side effects.
__device__ __forceinline__ unsigned sweep32(
    const float4* __restrict__ pmc, float x0, float x1, float x2,
    float M, float thr, float& sE, float& qE) {
  unsigned m = 0u;
#pragma unroll 8
  for (int i = 0; i < 32; ++i) {
    float4 a = pmc[i];
    const float l = fmaf(a.x, x0, fmaf(a.y, x1, fmaf(a.z, x2, a.w)));
    const float d = l - M;
    const float e = exp2f(d);   // far comps underflow to 0: harmless, exact-er
    sE += e;
    qE = fmaf(e, d, qE);
    m = (m >> 1) | ((l >= thr) ? 0x80000000u : 0u);
  }
  return m;
}

// ---------------------------------------------------------------------------
// Prep: fold sigma/mu/w into packed pm, base-2 scaled (each exp = v_exp_f32).
// ---------------------------------------------------------------------------
__global__ __launch_bounds__(512) void k_prep(
    const float* __restrict__ mu, const float* __restrict__ w,
    const float* __restrict__ sigma, float4* __restrict__ pm,
    float* __restrict__ ST, float* __restrict__ misc) {
  const int t = threadIdx.x;  // component id
  const float sg = sigma[0];
  const float k2 = L2E / (2.0f * sg * sg);  // log2e * inv2s2
  const float m0 = mu[3 * t], m1 = mu[3 * t + 1], m2 = mu[3 * t + 2];
  pm[t] = make_float4(2.0f * k2 * m0, 2.0f * k2 * m1, 2.0f * k2 * m2,
                      w[t] * L2E - (m0 * m0 + m1 * m1 + m2 * m2) * k2);
#pragma unroll
  for (int r = 0; r < NREP * 4; ++r) ST[r * 512 + t] = 0.f;
  if (t < 8) misc[t] = 0.f;
}

// ---------------------------------------------------------------------------
// E-step: block = 512 thr = 128 points x 4 comp-chunks (128 comps each).
// Pass 1 (dense): l + per-chunk max (no side effects).
// Pass 2a (dense, branchless): sE/qE + per-lane register hit-bitmasks.
// Pass 2b (compacted): walk set bits (~0.65/thread); push (p,c,l) into this
//   wave's private entry slice; base = wave-uniform SGPR counter. NO atomics.
// Pass 3: wave slices -> 4 global ST atomics + plist id write per entry.
// ---------------------------------------------------------------------------
__global__ __launch_bounds__(512, 4) void k_estep(
    const float* __restrict__ X, const float4* __restrict__ pm,
    float* __restrict__ ST, float* __restrict__ misc,
    float* __restrict__ out, unsigned short* __restrict__ plist) {
  __shared__ float4 s_pt[128];      // x0,x1,x2, (.w = z after combine)
  __shared__ float  s_m[4][128];    // per-(chunk,point) max
  __shared__ float2 s_sq[4][128];   // per-(chunk,point) (sumexp, q)
  __shared__ float  s_M[128];       // per-point global max
  __shared__ unsigned s_wcnt[8];    // per-wave entry count
  __shared__ unsigned s_pcnt[128];
  __shared__ unsigned s_ec[ECAP];   // packed (p<<16)|c, per-wave slices
  __shared__ float    s_el[ECAP];   // l for that entry

  const int t = threadIdx.x;
  const int p = t & 127;
  const int ch = __builtin_amdgcn_readfirstlane(t >> 7);  // wave-uniform
  const int wv = t >> 6;                                  // wave id 0..7
  const unsigned wbase = (unsigned)wv * WSL;
  const int n = blockIdx.x * 128 + p;
  const float x0 = X[3 * n], x1 = X[3 * n + 1], x2 = X[3 * n + 2];

  if (t < 128) {
    s_pcnt[t] = 0u;
    s_pt[t] = make_float4(x0, x1, x2, 0.f);  // p == t here
  }

  // --- pass 1: dense l + chunk max (no storage, no side effects) ---
  const float4* __restrict__ pmc = pm + ch * 128;  // wave-uniform
  float ma = -FLT_MAX, mb = -FLT_MAX, mc2 = -FLT_MAX, md = -FLT_MAX;
#pragma unroll 4
  for (int i = 0; i < 128; i += 4) {
    float4 a = pmc[i], b = pmc[i + 1], c = pmc[i + 2], d = pmc[i + 3];
    ma  = fmaxf(ma,  fmaf(a.x, x0, fmaf(a.y, x1, fmaf(a.z, x2, a.w))));
    mb  = fmaxf(mb,  fmaf(b.x, x0, fmaf(b.y, x1, fmaf(b.z, x2, b.w))));
    mc2 = fmaxf(mc2, fmaf(c.x, x0, fmaf(c.y, x1, fmaf(c.z, x2, c.w))));
    md  = fmaxf(md,  fmaf(d.x, x0, fmaf(d.y, x1, fmaf(d.z, x2, d.w))));
  }
  s_m[ch][p] = fmaxf(fmaxf(ma, mb), fmaxf(mc2, md));
  __syncthreads();  // B1 (also publishes init writes)

  if (t < 128) {
    s_M[t] = fmaxf(fmaxf(s_m[0][t], s_m[1][t]), fmaxf(s_m[2][t], s_m[3][t]));
  }
  __syncthreads();  // B2

  const float M = s_M[p];
  const float thr = M - CUT;
  const unsigned cbase = (unsigned)(ch * 128);

  // --- pass 2a: dense branchless sweeps -> sE/qE + hit masks ---
  float sE = 0.f, qE = 0.f;
  const unsigned mk0 = sweep32(pmc +  0, x0, x1, x2, M, thr, sE, qE);
  const unsigned mk1 = sweep32(pmc + 32, x0, x1, x2, M, thr, sE, qE);
  const unsigned mk2 = sweep32(pmc + 64, x0, x1, x2, M, thr, sE, qE);
  const unsigned mk3 = sweep32(pmc + 96, x0, x1, x2, M, thr, sE, qE);
  s_sq[ch][p] = make_float2(sE, qE);

  // --- pass 2b: compacted push into this wave's slice (no atomics) ---
  unsigned long long mA = (unsigned long long)mk0 |
                          ((unsigned long long)mk1 << 32);  // comps [0,64)
  unsigned long long mB = (unsigned long long)mk2 |
                          ((unsigned long long)mk3 << 32);  // comps [64,128)
  unsigned wcnt = 0u;  // wave-uniform (derived from ballot/popc -> scalar)

#define PROC(mreg, cb)                                                       \
  while (true) {                                                             \
    const unsigned long long wm = __ballot((mreg) != 0ull);                  \
    if (!wm) break;                                                          \
    const bool act = ((mreg) != 0ull);                                       \
    unsigned ii = 0u;                                                        \
    if (act) { ii = (unsigned)__builtin_ctzll(mreg); (mreg) &= (mreg) - 1; } \
    const unsigned pos = wcnt + lanePrefix(wm);                              \
    wcnt += (unsigned)__popcll(wm);                                          \
    if (act && pos < (unsigned)WSL) {                                        \
      const unsigned c = (cb) + ii;                                          \
      const float4 a = pm[c];                                                \
      const float l = fmaf(a.x, x0, fmaf(a.y, x1, fmaf(a.z, x2, a.w)));      \
      s_ec[wbase + pos] = ((unsigned)p << 16) | c;                           \
      s_el[wbase + pos] = l;                                                 \
    }                                                                        \
  }

  PROC(mA, cbase)
  PROC(mB, cbase + 64u)
#undef PROC

  if ((t & 63) == 0) s_wcnt[wv] = wcnt;
  __syncthreads();  // B3

  if (t < 128) {  // p == t: combine chunks; emit z, La, reductions
    float2 q0 = s_sq[0][t], q1 = s_sq[1][t], q2 = s_sq[2][t], q3 = s_sq[3][t];
    const float ss = (q0.x + q1.x) + (q2.x + q3.x);  // >= 1 (max term present)
    const float qq = (q0.y + q1.y) + (q2.y + q3.y);
    const float lg = __log2f(ss);
    const float z = s_M[t] + lg;
    s_pt[t].w = z;
    out[3 * n] = z;  // staged for k_final (base-2)
    const float La = LN2 * (__fdividef(qq, ss) - lg);  // sum_c gamma*lgamma
    const float xx = x0 * x0 + x1 * x1 + x2 * x2;
    const float rl = waveSum(La);
    const float rx = waveSum(xx);
    if ((t & 63) == 0) { atomicAdd(&misc[3], rl); atomicAdd(&misc[0], rx); }
  }
  __syncthreads();  // B4: s_ec/s_el/s_wcnt/s_pt.w all visible

  // --- pass 3: wave slices -> global ST atomics + plist ids ---
  float* __restrict__ stbase = ST + ((blockIdx.x & (NREP - 1)) * 512) * 4;
  const int bn = blockIdx.x * 128;
#pragma unroll
  for (unsigned idx = (unsigned)t; idx < (unsigned)ECAP; idx += 512u) {
    const unsigned w2 = idx >> 8;            // WSL == 256
    const unsigned j = idx & (WSL - 1u);
    if (j < s_wcnt[w2]) {
      const unsigned ec = s_ec[idx];
      const unsigned pp = ec >> 16;
      const unsigned c = ec & 0xFFFFu;
      const float4 pt = s_pt[pp];
      const float g = exp2f(s_el[idx] - pt.w);
      float* st = stbase + c * 4;
      atomicAdd(st + 0, g * pt.x);
      atomicAdd(st + 1, g * pt.y);
      atomicAdd(st + 2, g * pt.z);
      atomicAdd(st + 3, g);
      if (plist) {
        const unsigned slot = atomicAdd(&s_pcnt[pp], 1u);
        if (slot < (unsigned)PK)
          plist[(size_t)(bn + pp) * 16u + 1u + slot] = (unsigned short)c;
      }
    }
  }
  __syncthreads();  // B5: s_pcnt final
  if (plist && t < 128) {
    const unsigned pc = s_pcnt[t];
    plist[(size_t)(bn + t) * 16u] =
        (pc > (unsigned)PK) ? (unsigned short)0xFFFFu : (unsigned short)pc;
  }
}

// ---------------------------------------------------------------------------
// M-step: one block, 512 threads (one per component). Unchanged math.
// ---------------------------------------------------------------------------
__global__ __launch_bounds__(512) void k_mstep(
    const float* __restrict__ mu, const float4* __restrict__ ST4,
    float4* __restrict__ pq, float* __restrict__ misc,
    float* __restrict__ out) {
  __shared__ float s_red[8];
  __shared__ float s_red2[8];
  __shared__ float s_bc[4];
  const int t = threadIdx.x;

  float Tx = 0.f, Ty = 0.f, Tz = 0.f, S = 0.f;
#pragma unroll
  for (int r = 0; r < NREP; ++r) {
    float4 v = ST4[r * 512 + t];
    Tx += v.x; Ty += v.y; Tz += v.z; S += v.w;
  }
  const float Sc = fmaxf(S, 1e-30f);
  const float h = __logf(Sc);
  const float m0 = Tx / Sc, m1 = Ty / Sc, m2 = Tz / Sc;

  const float o0 = mu[3 * t], o1 = mu[3 * t + 1], o2 = mu[3 * t + 2];
  const float gdp = S * (o0 * o0 + o1 * o1 + o2 * o2)
                    - 2.0f * (o0 * Tx + o1 * Ty + o2 * Tz);

  float hm = waveMax(h);
  if ((t & 63) == 0) s_red[t >> 6] = hm;
  __syncthreads();
  if (t == 0) {
    float v = s_red[0];
    for (int i = 1; i < 8; ++i) v = fmaxf(v, s_red[i]);
    s_bc[0] = v;
  }
  __syncthreads();
  const float hM = s_bc[0];

  float es = waveSum(__expf(h - hM));
  float gs = waveSum(gdp);
  if ((t & 63) == 0) { s_red[t >> 6] = es; s_red2[t >> 6] = gs; }
  __syncthreads();
  if (t == 0) {
    float esum = 0.f, gsum = 0.f;
    for (int i = 0; i < 8; ++i) { esum += s_red[i]; gsum += s_red2[i]; }
    s_bc[1] = hM + __logf(esum);                           // lse(h)
    const float gd = fmaxf(misc[0] + gsum, 1e-20f);
    const float sn2 = gd * (1.0f / (3.0f * (float)NPTS));  // sigma_new^2
    s_bc[2] = 1.0f / (2.0f * sn2);                         // inv2s2_new
    s_bc[3] = 1.5f * __logf(sn2);                          // d*log(sigma_new)
  }
  __syncthreads();

  const float inv2s2n = s_bc[2];
  const float logpi = h - s_bc[1];
  const float A = (m0 * m0 + m1 * m1 + m2 * m2) * inv2s2n - logpi;
  pq[t] = make_float4(m0, m1, m2, A);

  float ca = waveSum(S * A);
  if ((t & 63) == 0) s_red[t >> 6] = ca;
  __syncthreads();
  if (t == 0) {
    float v = 0.f;
    for (int i = 0; i < 8; ++i) v += s_red[i];
    out[NPTS * 3] = v + misc[3] + (float)NPTS * s_bc[3];
    misc[1] = inv2s2n;
  }
}

// ---------------------------------------------------------------------------
// Final (list): thread-per-point, 512/block. Reads the per-point id list
// (avg ~2.6 comps); pm/pq LDS-staged. cnt=0xFFFF -> per-lane dense fallback.
// ---------------------------------------------------------------------------
__global__ __launch_bounds__(512, 4) void k_final_list(
    const float* __restrict__ X, const float4* __restrict__ pm,
    const float4* __restrict__ pq, const float* __restrict__ misc,
    float* __restrict__ out, const unsigned short* __restrict__ plist) {
  __shared__ float4 s_pm[NC];
  __shared__ float4 s_pq[NC];
  __shared__ float  s_red[8];

  const int t = threadIdx.x;
  const int n = blockIdx.x * 512 + t;

  s_pm[t] = pm[t];
  s_pq[t] = pq[t];

  const float x0 = X[3 * n], x1 = X[3 * n + 1], x2 = X[3 * n + 2];
  const float z = out[3 * n];  // staged by k_estep (base-2)
  const float inv2s2n = misc[1];

  const uint4* __restrict__ lp =
      reinterpret_cast<const uint4*>(plist) + ((size_t)n << 1);
  const uint4 wA = lp[0];
  const uint4 wB = lp[1];
  unsigned int words[8] = {wA.x, wA.y, wA.z, wA.w, wB.x, wB.y, wB.z, wB.w};
  const unsigned int cnt = words[0] & 0xFFFFu;
  __syncthreads();

  float y0 = 0.f, y1 = 0.f, y2 = 0.f;
  if (cnt == 0xFFFFu) {
    // dense fallback for overflowed points (astronomically rare)
    const float thr = z - CUT;
    for (int c = 0; c < NC; ++c) {
      float4 pp = s_pm[c];
      const float l = fmaf(pp.x, x0, fmaf(pp.y, x1, fmaf(pp.z, x2, pp.w)));
      if (l >= thr) {
        const float g = exp2f(l - z);
        float4 qq = s_pq[c];
        y0 = fmaf(g, qq.x, y0);
        y1 = fmaf(g, qq.y, y1);
        y2 = fmaf(g, qq.z, y2);
      }
    }
  } else {
    const int ic = (int)cnt;
#pragma unroll
    for (int j = 0; j < PK; ++j) {
      if (!__any(j < ic)) break;  // wave-uniform early exit (max cnt ~6)
      if (j < ic) {
        const unsigned int word = words[(j + 1) >> 1];
        const unsigned int c =
            ((j + 1) & 1) ? (word >> 16) : (word & 0xFFFFu);
        float4 pp = s_pm[c];
        const float l = fmaf(pp.x, x0, fmaf(pp.y, x1, fmaf(pp.z, x2, pp.w)));
        const float g = exp2f(l - z);
        float4 qq = s_pq[c];
        y0 = fmaf(g, qq.x, y0);
        y1 = fmaf(g, qq.y, y1);
        y2 = fmaf(g, qq.z, y2);
      }
    }
  }

  const float cfe = -(y0 * y0 + y1 * y1 + y2 * y2) * inv2s2n;
  out[3 * n] = y0;
  out[3 * n + 1] = y1;
  out[3 * n + 2] = y2;

  float r = waveSum(cfe);
  if ((t & 63) == 0) s_red[t >> 6] = r;
  __syncthreads();
  if (t == 0) {
    float v = 0.f;
#pragma unroll
    for (int i = 0; i < 8; ++i) v += s_red[i];
    atomicAdd(&out[NPTS * 3], v);
  }
}

// ---------------------------------------------------------------------------
// Final (dense, round-0 structure, base-2): fallback if ws too small.
// ---------------------------------------------------------------------------
__global__ __launch_bounds__(512, 8) void k_final_dense(
    const float* __restrict__ X, const float4* __restrict__ pm,
    const float4* __restrict__ pq, const float* __restrict__ misc,
    float* __restrict__ out) {
  __shared__ float4 s_y[4][128];
  __shared__ float  s_red[8];

  const int t = threadIdx.x;
  const int p = t & 127;
  const int ch = __builtin_amdgcn_readfirstlane(t >> 7);
  const int n = blockIdx.x * 128 + p;
  const float x0 = X[3 * n], x1 = X[3 * n + 1], x2 = X[3 * n + 2];
  const float z = out[3 * n];
  const float inv2s2n = misc[1];

  const float4* __restrict__ pmc = pm + ch * 128;
  const float4* __restrict__ pqc = pq + ch * 128;
  float y0 = 0.f, y1 = 0.f, y2 = 0.f;
#pragma unroll 4
  for (int i = 0; i < 128; ++i) {
    float4 pp = pmc[i];
    float4 qq = pqc[i];
    const float l = fmaf(pp.x, x0, fmaf(pp.y, x1, fmaf(pp.z, x2, pp.w))) - z;
    const float g = exp2f(l);
    y0 = fmaf(g, qq.x, y0);
    y1 = fmaf(g, qq.y, y1);
    y2 = fmaf(g, qq.z, y2);
  }
  s_y[ch][p] = make_float4(y0, y1, y2, 0.f);
  __syncthreads();

  float cfe = 0.f;
  if (t < 128) {
    float4 a0 = s_y[0][t], a1 = s_y[1][t], a2 = s_y[2][t], a3 = s_y[3][t];
    const float Y0 = (a0.x + a1.x) + (a2.x + a3.x);
    const float Y1 = (a0.y + a1.y) + (a2.y + a3.y);
    const float Y2 = (a0.z + a1.z) + (a2.z + a3.z);
    cfe = -(Y0 * Y0 + Y1 * Y1 + Y2 * Y2) * inv2s2n;
    out[3 * n] = Y0;
    out[3 * n + 1] = Y1;
    out[3 * n + 2] = Y2;
  }
  float r = waveSum(cfe);
  if ((t & 63) == 0) s_red[t >> 6] = r;
  __syncthreads();
  if (t == 0) {
    float v = 0.f;
#pragma unroll
    for (int i = 0; i < 8; ++i) v += s_red[i];
    atomicAdd(&out[NPTS * 3], v);
  }
}

extern "C" void kernel_launch(void* const* d_in, const int* in_sizes, int n_in,
                              void* d_out, int out_size, void* d_ws, size_t ws_size,
                              hipStream_t stream) {
  const float* X = (const float*)d_in[0];
  const float* mu = (const float*)d_in[1];
  const float* w = (const float*)d_in[2];
  const float* sigma = (const float*)d_in[3];
  float* out = (float*)d_out;
  float* ws = (float*)d_ws;

  float4* pm = (float4*)(ws + PM4_OFF);
  float4* pq = (float4*)(ws + PQ4_OFF);
  float* ST = ws + ST4_OFF;
  float* misc = ws + MISC_OFF;

  const size_t need = (size_t)PL_OFF * 4 + (size_t)NPTS * 32;  // ~4.26 MB
  unsigned short* plist =
      (ws_size >= need) ? (unsigned short*)(ws + PL_OFF) : (unsigned short*)0;

  k_prep<<<1, 512, 0, stream>>>(mu, w, sigma, pm, ST, misc);
  k_estep<<<NPTS / 128, 512, 0, stream>>>(X, pm, ST, misc, out, plist);
  k_mstep<<<1, 512, 0, stream>>>(mu, (const float4*)ST, pq, misc, out);
  if (plist)
    k_final_list<<<NPTS / 512, 512, 0, stream>>>(X, pm, pq, misc, out, plist);
  else
    k_final_dense<<<NPTS / 128, 512, 0, stream>>>(X, pm, pq, misc, out);
}

// Round 5
// 146.402 us; speedup vs baseline: 1.1347x; 1.1347x over previous
//
#include <hip/hip_runtime.h>
#include <cfloat>
#include <cmath>

#define NPTS 131072
#define NC   512
#define NREP 4
// natural-log relevance cutoff: gamma < e^-34 ~ 1.7e-15 is negligible.
// Validated across rounds 0-4: absmax identical with/without the cut.
#define CUT  34.0f
#define PK   15     // per-point id slots (overflow -> dense fallback in final)

// ws float-index layout:
//  PM4  [0, 2048)      : per-component float4 (2*mu/2s2, w - |mu|^2/2s2)
//  PQ4  [2048, 4096)   : per-component float4 (mu_new[3], A_c)
//  ST4  [4096, 12288)  : NREP replicas x 512 comps x float4 (Tx,Ty,Tz,S)
//  MISC [12288, 12296) : [0]=sum|x|^2, [1]=inv2s2_new, [3]=sum(gamma*lgamma)
//  PL   [16384, ...)   : per-point u16[16]: [cnt|0xFFFF, id0..id14]  (4 MB)
// z_n staged in d_out[3n] (k_estep writes, k_final reads then overwrites).
#define PM4_OFF  0
#define PQ4_OFF  2048
#define ST4_OFF  4096
#define MISC_OFF 12288
#define PL_OFF   16384

__device__ __forceinline__ float waveSum(float v) {
#pragma unroll
  for (int off = 32; off > 0; off >>= 1) v += __shfl_down(v, off, 64);
  return v;
}
__device__ __forceinline__ float waveMax(float v) {
#pragma unroll
  for (int off = 32; off > 0; off >>= 1) v = fmaxf(v, __shfl_down(v, off, 64));
  return v;
}

// ---------------------------------------------------------------------------
// Prep: fold sigma/mu/w into packed pm; zero ST replicas + misc. (round-0)
// ---------------------------------------------------------------------------
__global__ __launch_bounds__(512) void k_prep(
    const float* __restrict__ mu, const float* __restrict__ w,
    const float* __restrict__ sigma, float4* __restrict__ pm,
    float* __restrict__ ST, float* __restrict__ misc) {
  const int t = threadIdx.x;  // component id
  const float sg = sigma[0];
  const float inv2s2 = 1.0f / (2.0f * sg * sg);
  const float m0 = mu[3 * t], m1 = mu[3 * t + 1], m2 = mu[3 * t + 2];
  pm[t] = make_float4(2.0f * inv2s2 * m0, 2.0f * inv2s2 * m1, 2.0f * inv2s2 * m2,
                      w[t] - (m0 * m0 + m1 * m1 + m2 * m2) * inv2s2);
#pragma unroll
  for (int r = 0; r < NREP * 4; ++r) ST[r * 512 + t] = 0.f;
  if (t < 8) misc[t] = 0.f;
}

// ---------------------------------------------------------------------------
// E-step: EXACT round-0 structure (58us, 75% busy) + minimal list emission.
// Phase A: per-chunk (max, sumexp) -> LDS combine -> z_n.
// Phase C: thread owns ONE comp over the 128 points (LDS broadcast reads).
//   Added: per-iteration __ballot(hit) is the per-(point, 64-comp-group) hit
//   mask (lanes of a wave = 64 consecutive comps, same point). Lane 0 stores
//   it to s_hits[wave][point]; the exp+FMA tail is skipped when mask==0
//   (wave-uniform, register-only body). Atomics to replica blockIdx&3.
// Tail: 128 threads materialize plist from s_hits (bit-walk, no atomics).
// ---------------------------------------------------------------------------
__global__ __launch_bounds__(512, 8) void k_estep(
    const float* __restrict__ X, const float4* __restrict__ pm,
    float* __restrict__ ST, float* __restrict__ misc,
    float* __restrict__ out, unsigned short* __restrict__ plist) {
  __shared__ float4 s_pt[128];     // (x0,x1,x2,z)
  __shared__ float2 s_ms[4][128];  // per-chunk (max, sumexp)
  __shared__ float  s_red[8];
  __shared__ float  s_red2[8];
  __shared__ unsigned long long s_hits[8][128];  // [wave(comp-group)][point]

  const int t = threadIdx.x;
  const int p = t & 127;
  const int ch = __builtin_amdgcn_readfirstlane(t >> 7);  // wave-uniform
  const int wv = t >> 6;                                  // wave id 0..7
  const int n = blockIdx.x * 128 + p;
  const float x0 = X[3 * n], x1 = X[3 * n + 1], x2 = X[3 * n + 2];

  // --- phase A: partial max / sumexp over this chunk's 128 comps ---
  const float4* __restrict__ pmc = pm + ch * 128;
  float ma = -FLT_MAX, mb = -FLT_MAX, mc = -FLT_MAX, md = -FLT_MAX;
#pragma unroll 4
  for (int i = 0; i < 128; i += 4) {
    float4 a = pmc[i], b = pmc[i + 1], c = pmc[i + 2], d = pmc[i + 3];
    ma = fmaxf(ma, fmaf(a.x, x0, fmaf(a.y, x1, fmaf(a.z, x2, a.w))));
    mb = fmaxf(mb, fmaf(b.x, x0, fmaf(b.y, x1, fmaf(b.z, x2, b.w))));
    mc = fmaxf(mc, fmaf(c.x, x0, fmaf(c.y, x1, fmaf(c.z, x2, c.w))));
    md = fmaxf(md, fmaf(d.x, x0, fmaf(d.y, x1, fmaf(d.z, x2, d.w))));
  }
  const float m = fmaxf(fmaxf(ma, mb), fmaxf(mc, md));
  float sa = 0.f, sb = 0.f, sc = 0.f, sd = 0.f;
#pragma unroll 4
  for (int i = 0; i < 128; i += 4) {
    float4 a = pmc[i], b = pmc[i + 1], c = pmc[i + 2], d = pmc[i + 3];
    sa += __expf(fmaf(a.x, x0, fmaf(a.y, x1, fmaf(a.z, x2, a.w))) - m);
    sb += __expf(fmaf(b.x, x0, fmaf(b.y, x1, fmaf(b.z, x2, b.w))) - m);
    sc += __expf(fmaf(c.x, x0, fmaf(c.y, x1, fmaf(c.z, x2, c.w))) - m);
    sd += __expf(fmaf(d.x, x0, fmaf(d.y, x1, fmaf(d.z, x2, d.w))) - m);
  }
  s_ms[ch][p] = make_float2(m, (sa + sb) + (sc + sd));
  __syncthreads();

  if (t < 128) {  // thread t owns point p == t here
    float2 q0 = s_ms[0][t], q1 = s_ms[1][t], q2 = s_ms[2][t], q3 = s_ms[3][t];
    float M = fmaxf(fmaxf(q0.x, q1.x), fmaxf(q2.x, q3.x));
    float SS = q0.y * __expf(q0.x - M) + q1.y * __expf(q1.x - M) +
               q2.y * __expf(q2.x - M) + q3.y * __expf(q3.x - M);
    float z = M + __logf(SS);
    s_pt[t] = make_float4(x0, x1, x2, z);
    out[3 * n] = z;  // staged for k_final
  }
  __syncthreads();

  // --- phase C: thread t owns comp t across the block's 128 points ---
  const float4 pc = pm[t];  // coalesced per-lane load
  float Sg = 0.f, Tx = 0.f, Ty = 0.f, Tz = 0.f, La = 0.f;
#pragma unroll 4
  for (int i = 0; i < 128; ++i) {
    float4 pt = s_pt[i];  // broadcast read
    float l = fmaf(pc.x, pt.x, fmaf(pc.y, pt.y, fmaf(pc.z, pt.z, pc.w)));
    float d = l - pt.w;   // lgamma
    const unsigned long long mask = __ballot(d >= -CUT);
    if ((t & 63) == 0) s_hits[wv][i] = mask;  // exec-masked ds_write_b64
    if (mask) {  // wave-uniform skip; body is register-only
      float g = __expf(d);
      Sg += g;
      Tx = fmaf(g, pt.x, Tx);
      Ty = fmaf(g, pt.y, Ty);
      Tz = fmaf(g, pt.z, Tz);
      La = fmaf(g, d, La);  // sum gamma * lgamma
    }
  }
  float* st = ST + (((blockIdx.x & (NREP - 1)) * 512 + t) << 2);
  atomicAdd(st + 0, Tx);
  atomicAdd(st + 1, Ty);
  atomicAdd(st + 2, Tz);
  atomicAdd(st + 3, Sg);

  // --- block reduce: sum|x|^2 (points counted once via t<128) and La ---
  float xx = (t < 128) ? (x0 * x0 + x1 * x1 + x2 * x2) : 0.f;
  float rx = waveSum(xx);
  float rl = waveSum(La);
  if ((t & 63) == 0) { s_red[t >> 6] = rx; s_red2[t >> 6] = rl; }
  __syncthreads();  // also publishes s_hits for the materializer
  if (t == 0) {
    float vx = 0.f, vl = 0.f;
#pragma unroll
    for (int i = 0; i < 8; ++i) { vx += s_red[i]; vl += s_red2[i]; }
    atomicAdd(&misc[0], vx);
    atomicAdd(&misc[3], vl);
  }

  // --- materialize per-point id lists (no atomics; sequential u16 stores) ---
  if (plist != 0 && t < 128) {
    unsigned short* q = plist + (size_t)n * 16u;  // n uses p == t
    unsigned cnt = 0u;
#pragma unroll
    for (int w = 0; w < 8; ++w) {
      unsigned long long hm = s_hits[w][t];
      while (hm) {
        const unsigned b = (unsigned)__builtin_ctzll(hm);
        hm &= hm - 1;
        if (cnt < (unsigned)PK) q[1 + cnt] = (unsigned short)(w * 64 + b);
        ++cnt;
      }
    }
    q[0] = (cnt > (unsigned)PK) ? (unsigned short)0xFFFFu
                                : (unsigned short)cnt;
  }
}

// ---------------------------------------------------------------------------
// M-step: one block, 512 threads (one per component). Unchanged math.
// ---------------------------------------------------------------------------
__global__ __launch_bounds__(512) void k_mstep(
    const float* __restrict__ mu, const float4* __restrict__ ST4,
    float4* __restrict__ pq, float* __restrict__ misc,
    float* __restrict__ out) {
  __shared__ float s_red[8];
  __shared__ float s_red2[8];
  __shared__ float s_bc[4];
  const int t = threadIdx.x;

  float Tx = 0.f, Ty = 0.f, Tz = 0.f, S = 0.f;
#pragma unroll
  for (int r = 0; r < NREP; ++r) {
    float4 v = ST4[r * 512 + t];
    Tx += v.x; Ty += v.y; Tz += v.z; S += v.w;
  }
  const float Sc = fmaxf(S, 1e-30f);
  const float h = __logf(Sc);
  const float m0 = Tx / Sc, m1 = Ty / Sc, m2 = Tz / Sc;

  const float o0 = mu[3 * t], o1 = mu[3 * t + 1], o2 = mu[3 * t + 2];
  const float gdp = S * (o0 * o0 + o1 * o1 + o2 * o2)
                    - 2.0f * (o0 * Tx + o1 * Ty + o2 * Tz);

  float hm = waveMax(h);
  if ((t & 63) == 0) s_red[t >> 6] = hm;
  __syncthreads();
  if (t == 0) {
    float v = s_red[0];
    for (int i = 1; i < 8; ++i) v = fmaxf(v, s_red[i]);
    s_bc[0] = v;
  }
  __syncthreads();
  const float hM = s_bc[0];

  float es = waveSum(__expf(h - hM));
  float gs = waveSum(gdp);
  if ((t & 63) == 0) { s_red[t >> 6] = es; s_red2[t >> 6] = gs; }
  __syncthreads();
  if (t == 0) {
    float esum = 0.f, gsum = 0.f;
    for (int i = 0; i < 8; ++i) { esum += s_red[i]; gsum += s_red2[i]; }
    s_bc[1] = hM + __logf(esum);                           // lse(h)
    const float gd = fmaxf(misc[0] + gsum, 1e-20f);
    const float sn2 = gd * (1.0f / (3.0f * (float)NPTS));  // sigma_new^2
    s_bc[2] = 1.0f / (2.0f * sn2);                         // inv2s2_new
    s_bc[3] = 1.5f * __logf(sn2);                          // d*log(sigma_new)
  }
  __syncthreads();

  const float inv2s2n = s_bc[2];
  const float logpi = h - s_bc[1];
  const float A = (m0 * m0 + m1 * m1 + m2 * m2) * inv2s2n - logpi;
  pq[t] = make_float4(m0, m1, m2, A);

  float ca = waveSum(S * A);
  if ((t & 63) == 0) s_red[t >> 6] = ca;
  __syncthreads();
  if (t == 0) {
    float v = 0.f;
    for (int i = 0; i < 8; ++i) v += s_red[i];
    out[NPTS * 3] = v + misc[3] + (float)NPTS * s_bc[3];
    misc[1] = inv2s2n;
  }
}

// ---------------------------------------------------------------------------
// Final (list): thread-per-point, 512/block. Reads the per-point id list
// (avg ~3.5 comps); pm/pq LDS-staged. cnt=0xFFFF -> per-lane dense fallback.
// ---------------------------------------------------------------------------
__global__ __launch_bounds__(512, 4) void k_final_list(
    const float* __restrict__ X, const float4* __restrict__ pm,
    const float4* __restrict__ pq, const float* __restrict__ misc,
    float* __restrict__ out, const unsigned short* __restrict__ plist) {
  __shared__ float4 s_pm[NC];
  __shared__ float4 s_pq[NC];
  __shared__ float  s_red[8];

  const int t = threadIdx.x;
  const int n = blockIdx.x * 512 + t;

  s_pm[t] = pm[t];
  s_pq[t] = pq[t];

  const float x0 = X[3 * n], x1 = X[3 * n + 1], x2 = X[3 * n + 2];
  const float z = out[3 * n];  // staged by k_estep (natural log)
  const float inv2s2n = misc[1];

  const uint4* __restrict__ lp =
      reinterpret_cast<const uint4*>(plist) + ((size_t)n << 1);
  const uint4 wA = lp[0];
  const uint4 wB = lp[1];
  unsigned int words[8] = {wA.x, wA.y, wA.z, wA.w, wB.x, wB.y, wB.z, wB.w};
  const unsigned int cnt = words[0] & 0xFFFFu;
  __syncthreads();

  float y0 = 0.f, y1 = 0.f, y2 = 0.f;
  if (cnt == 0xFFFFu) {
    // dense fallback for overflowed points (rare)
    const float thr = z - CUT;
    for (int c = 0; c < NC; ++c) {
      float4 pp = s_pm[c];
      const float l = fmaf(pp.x, x0, fmaf(pp.y, x1, fmaf(pp.z, x2, pp.w)));
      if (l >= thr) {
        const float g = __expf(l - z);
        float4 qq = s_pq[c];
        y0 = fmaf(g, qq.x, y0);
        y1 = fmaf(g, qq.y, y1);
        y2 = fmaf(g, qq.z, y2);
      }
    }
  } else {
    const int ic = (int)cnt;
#pragma unroll
    for (int j = 0; j < PK; ++j) {
      if (!__any(j < ic)) break;  // wave-uniform early exit
      if (j < ic) {
        const unsigned int word = words[(j + 1) >> 1];
        const unsigned int c =
            ((j + 1) & 1) ? (word >> 16) : (word & 0xFFFFu);
        float4 pp = s_pm[c];
        const float l = fmaf(pp.x, x0, fmaf(pp.y, x1, fmaf(pp.z, x2, pp.w)));
        const float g = __expf(l - z);
        float4 qq = s_pq[c];
        y0 = fmaf(g, qq.x, y0);
        y1 = fmaf(g, qq.y, y1);
        y2 = fmaf(g, qq.z, y2);
      }
    }
  }

  const float cfe = -(y0 * y0 + y1 * y1 + y2 * y2) * inv2s2n;
  out[3 * n] = y0;
  out[3 * n + 1] = y1;
  out[3 * n + 2] = y2;

  float r = waveSum(cfe);
  if ((t & 63) == 0) s_red[t >> 6] = r;
  __syncthreads();
  if (t == 0) {
    float v = 0.f;
#pragma unroll
    for (int i = 0; i < 8; ++i) v += s_red[i];
    atomicAdd(&out[NPTS * 3], v);
  }
}

// ---------------------------------------------------------------------------
// Final (dense, round-0 structure): fallback if ws too small for plist.
// ---------------------------------------------------------------------------
__global__ __launch_bounds__(512, 8) void k_final_dense(
    const float* __restrict__ X, const float4* __restrict__ pm,
    const float4* __restrict__ pq, const float* __restrict__ misc,
    float* __restrict__ out) {
  __shared__ float4 s_y[4][128];
  __shared__ float  s_red[8];

  const int t = threadIdx.x;
  const int p = t & 127;
  const int ch = __builtin_amdgcn_readfirstlane(t >> 7);
  const int n = blockIdx.x * 128 + p;
  const float x0 = X[3 * n], x1 = X[3 * n + 1], x2 = X[3 * n + 2];
  const float z = out[3 * n];
  const float inv2s2n = misc[1];

  const float4* __restrict__ pmc = pm + ch * 128;
  const float4* __restrict__ pqc = pq + ch * 128;
  float y0 = 0.f, y1 = 0.f, y2 = 0.f;
#pragma unroll 4
  for (int i = 0; i < 128; ++i) {
    float4 pp = pmc[i];
    float4 qq = pqc[i];
    const float l = fmaf(pp.x, x0, fmaf(pp.y, x1, fmaf(pp.z, x2, pp.w))) - z;
    const float g = __expf(l);
    y0 = fmaf(g, qq.x, y0);
    y1 = fmaf(g, qq.y, y1);
    y2 = fmaf(g, qq.z, y2);
  }
  s_y[ch][p] = make_float4(y0, y1, y2, 0.f);
  __syncthreads();

  float cfe = 0.f;
  if (t < 128) {
    float4 a0 = s_y[0][t], a1 = s_y[1][t], a2 = s_y[2][t], a3 = s_y[3][t];
    const float Y0 = (a0.x + a1.x) + (a2.x + a3.x);
    const float Y1 = (a0.y + a1.y) + (a2.y + a3.y);
    const float Y2 = (a0.z + a1.z) + (a2.z + a3.z);
    cfe = -(Y0 * Y0 + Y1 * Y1 + Y2 * Y2) * inv2s2n;
    out[3 * n] = Y0;
    out[3 * n + 1] = Y1;
    out[3 * n + 2] = Y2;
  }
  float r = waveSum(cfe);
  if ((t & 63) == 0) s_red[t >> 6] = r;
  __syncthreads();
  if (t == 0) {
    float v = 0.f;
#pragma unroll
    for (int i = 0; i < 8; ++i) v += s_red[i];
    atomicAdd(&out[NPTS * 3], v);
  }
}

extern "C" void kernel_launch(void* const* d_in, const int* in_sizes, int n_in,
                              void* d_out, int out_size, void* d_ws, size_t ws_size,
                              hipStream_t stream) {
  const float* X = (const float*)d_in[0];
  const float* mu = (const float*)d_in[1];
  const float* w = (const float*)d_in[2];
  const float* sigma = (const float*)d_in[3];
  float* out = (float*)d_out;
  float* ws = (float*)d_ws;

  float4* pm = (float4*)(ws + PM4_OFF);
  float4* pq = (float4*)(ws + PQ4_OFF);
  float* ST = ws + ST4_OFF;
  float* misc = ws + MISC_OFF;

  const size_t need = (size_t)PL_OFF * 4 + (size_t)NPTS * 32;  // ~4.26 MB
  unsigned short* plist =
      (ws_size >= need) ? (unsigned short*)(ws + PL_OFF) : (unsigned short*)0;

  k_prep<<<1, 512, 0, stream>>>(mu, w, sigma, pm, ST, misc);
  k_estep<<<NPTS / 128, 512, 0, stream>>>(X, pm, ST, misc, out, plist);
  k_mstep<<<1, 512, 0, stream>>>(mu, (const float4*)ST, pq, misc, out);
  if (plist)
    k_final_list<<<NPTS / 512, 512, 0, stream>>>(X, pm, pq, misc, out, plist);
  else
    k_final_dense<<<NPTS / 128, 512, 0, stream>>>(X, pm, pq, misc, out);
}